// Round 1
// baseline (857.497 us; speedup 1.0000x reference)
//
#include <hip/hip_runtime.h>
#include <hip/hip_bf16.h>

#define IN_DIM 1024
#define DK 512
#define DV 512
#define NQ 8192
#define NKV 8192
#define BQ 32
#define BKC 32

typedef _Float16 f16x8 __attribute__((ext_vector_type(8)));
typedef _Float16 f16x4 __attribute__((ext_vector_type(4)));
typedef float f32x4 __attribute__((ext_vector_type(4)));

// ---------------- projection: out = A @ W^T + b, stored f16 ----------------
// z=0: Q[N][DK] row-major; z=1: K[M][DK] row-major; z=2: Vt[DV][M] (transposed)
__global__ __launch_bounds__(256) void proj_kernel(
    const float* __restrict__ qin, const float* __restrict__ kin, const float* __restrict__ vin,
    const float* __restrict__ Wq, const float* __restrict__ bq,
    const float* __restrict__ Wk, const float* __restrict__ bk,
    const float* __restrict__ Wv, const float* __restrict__ bv,
    _Float16* __restrict__ Qb, _Float16* __restrict__ Kb, _Float16* __restrict__ Vt)
{
    const int z = blockIdx.z;
    const float* A  = (z == 0) ? qin : (z == 1) ? kin : vin;
    const float* W  = (z == 0) ? Wq  : (z == 1) ? Wk  : Wv;
    const float* bi = (z == 0) ? bq  : (z == 1) ? bk  : bv;

    __shared__ _Float16 As[128][72];   // +8 pad: bank shift 4/row
    __shared__ _Float16 Bs[128][72];

    const int tid = threadIdx.x;
    const int rowbase = blockIdx.y * 128;
    const int colbase = blockIdx.x * 128;
    const int wave = tid >> 6;
    const int lane = tid & 63;
    const int quad = lane >> 4;
    const int l16  = lane & 15;
    const int wrow = (wave & 1) * 64;
    const int wcol = (wave >> 1) * 64;

    f32x4 acc[4][4];
#pragma unroll
    for (int r = 0; r < 4; ++r)
#pragma unroll
        for (int c = 0; c < 4; ++c) acc[r][c] = (f32x4)(0.0f);

    for (int kc = 0; kc < IN_DIM / 64; ++kc) {
        __syncthreads();
#pragma unroll
        for (int i = 0; i < 8; ++i) {
            int idx = tid + i * 256;      // float4 units, 0..2047
            int row = idx >> 4;           // 16 float4 per 64-wide row
            int c4  = idx & 15;
            float4 ga = *(const float4*)&A[(size_t)(rowbase + row) * IN_DIM + kc * 64 + c4 * 4];
            f16x4 pa;
            pa[0] = (_Float16)ga.x; pa[1] = (_Float16)ga.y;
            pa[2] = (_Float16)ga.z; pa[3] = (_Float16)ga.w;
            *(f16x4*)&As[row][c4 * 4] = pa;
            float4 gb = *(const float4*)&W[(size_t)(colbase + row) * IN_DIM + kc * 64 + c4 * 4];
            f16x4 pb;
            pb[0] = (_Float16)gb.x; pb[1] = (_Float16)gb.y;
            pb[2] = (_Float16)gb.z; pb[3] = (_Float16)gb.w;
            *(f16x4*)&Bs[row][c4 * 4] = pb;
        }
        __syncthreads();
#pragma unroll
        for (int ks = 0; ks < 2; ++ks) {
            f16x8 af[4], bfr[4];
#pragma unroll
            for (int r = 0; r < 4; ++r)
                af[r] = *(const f16x8*)&As[wrow + r * 16 + l16][ks * 32 + quad * 8];
#pragma unroll
            for (int c = 0; c < 4; ++c)
                bfr[c] = *(const f16x8*)&Bs[wcol + c * 16 + l16][ks * 32 + quad * 8];
#pragma unroll
            for (int r = 0; r < 4; ++r)
#pragma unroll
                for (int c = 0; c < 4; ++c)
                    acc[r][c] = __builtin_amdgcn_mfma_f32_16x16x32_f16(af[r], bfr[c], acc[r][c], 0, 0, 0);
        }
    }

    if (z < 2) {
        _Float16* outp = (z == 0) ? Qb : Kb;
#pragma unroll
        for (int c = 0; c < 4; ++c) {
            int col = colbase + wcol + c * 16 + l16;
            float bval = bi[col];
#pragma unroll
            for (int r = 0; r < 4; ++r)
#pragma unroll
                for (int g = 0; g < 4; ++g) {
                    int row = rowbase + wrow + r * 16 + quad * 4 + g;
                    outp[(size_t)row * DK + col] = (_Float16)(acc[r][c][g] + bval);
                }
        }
    } else {
#pragma unroll
        for (int c = 0; c < 4; ++c) {
            int col = colbase + wcol + c * 16 + l16;   // feature index -> Vt row
            float bval = bi[col];
#pragma unroll
            for (int r = 0; r < 4; ++r) {
                int row0 = rowbase + wrow + r * 16 + quad * 4;   // 4 consecutive m's
                f16x4 pk;
#pragma unroll
                for (int g = 0; g < 4; ++g) pk[g] = (_Float16)(acc[r][c][g] + bval);
                *(f16x4*)&Vt[(size_t)col * NKV + row0] = pk;
            }
        }
    }
}

// ---------------- flash attention: out = softmax(Q K^T)/ * norm @ V --------
__global__ __launch_bounds__(512) void flash_kernel(
    const _Float16* __restrict__ Qb, const _Float16* __restrict__ Kb,
    const _Float16* __restrict__ Vt, float* __restrict__ out)
{
    __shared__ _Float16 Qs[BQ][520];     // 33280 B
    __shared__ _Float16 Ks[BKC][520];    // 33280 B
    __shared__ _Float16 Vts[DV][40];     // 40960 B
    __shared__ float    Ss[BQ][36];      //  4608 B
    __shared__ _Float16 Ps[BQ][40];      //  2560 B
    __shared__ float row_m[BQ], row_l[BQ], row_alpha[BQ];

    const int tid = threadIdx.x;
    const int qbase = blockIdx.x * BQ;
    const int wave = tid >> 6;
    const int lane = tid & 63;
    const int quad = lane >> 4;
    const int l16  = lane & 15;
    const int wcol = wave * 64;          // d_v slice per wave

    // Q tile: 32 x 512 halfs = 2048 x (8 halfs)
#pragma unroll
    for (int i = 0; i < 4; ++i) {
        int idx = tid + i * 512;
        int row = idx >> 6;
        int seg = idx & 63;
        *(uint4*)&Qs[row][seg * 8] = *(const uint4*)&Qb[(size_t)(qbase + row) * DK + seg * 8];
    }
    if (tid < BQ) { row_m[tid] = -1e30f; row_l[tid] = 0.0f; }

    f32x4 oacc[2][4];
#pragma unroll
    for (int r = 0; r < 2; ++r)
#pragma unroll
        for (int c = 0; c < 4; ++c) oacc[r][c] = (f32x4)(0.0f);

    for (int kb = 0; kb < NKV / BKC; ++kb) {
        const int keybase = kb * BKC;
        __syncthreads();   // prev chunk's Ks/Vts/Ps fully consumed
#pragma unroll
        for (int i = 0; i < 4; ++i) {
            int idx = tid + i * 512;
            int row = idx >> 6;
            int seg = idx & 63;
            *(uint4*)&Ks[row][seg * 8] = *(const uint4*)&Kb[(size_t)(keybase + row) * DK + seg * 8];
        }
#pragma unroll
        for (int i = 0; i < 4; ++i) {
            int idx = tid + i * 512;
            int j   = idx >> 2;          // Vt row (feature)
            int seg = idx & 3;
            *(uint4*)&Vts[j][seg * 8] = *(const uint4*)&Vt[(size_t)j * NKV + keybase + seg * 8];
        }
        __syncthreads();

        if (wave < 4) {                  // S tile 32x32, one 16x16 per wave
            const int rt = (wave & 1) * 16;
            const int ct = (wave >> 1) * 16;
            f32x4 s = (f32x4)(0.0f);
#pragma unroll
            for (int ks = 0; ks < 16; ++ks) {
                f16x8 aq = *(const f16x8*)&Qs[rt + l16][ks * 32 + quad * 8];
                f16x8 bk = *(const f16x8*)&Ks[ct + l16][ks * 32 + quad * 8];
                s = __builtin_amdgcn_mfma_f32_16x16x32_f16(aq, bk, s, 0, 0, 0);
            }
#pragma unroll
            for (int g = 0; g < 4; ++g)
                Ss[rt + quad * 4 + g][ct + l16] = s[g];
        }
        __syncthreads();

        if (tid < BQ) {                  // online softmax, 1 thread / row
            const int r = tid;
            float m_old = row_m[r];
            float mx = m_old;
#pragma unroll
            for (int j = 0; j < BKC; ++j) mx = fmaxf(mx, Ss[r][j]);
            float alpha = __expf(m_old - mx);
            float sum = 0.0f;
#pragma unroll
            for (int j = 0; j < BKC; ++j) {
                float p = __expf(Ss[r][j] - mx);
                sum += p;
                Ps[r][j] = (_Float16)p;
            }
            row_l[r] = row_l[r] * alpha + sum;
            row_m[r] = mx;
            row_alpha[r] = alpha;
        }
        __syncthreads();

        float al[2][4];
#pragma unroll
        for (int r = 0; r < 2; ++r)
#pragma unroll
            for (int g = 0; g < 4; ++g)
                al[r][g] = row_alpha[r * 16 + quad * 4 + g];
        f16x8 pf[2];
#pragma unroll
        for (int r = 0; r < 2; ++r)
            pf[r] = *(const f16x8*)&Ps[r * 16 + l16][quad * 8];
#pragma unroll
        for (int c = 0; c < 4; ++c) {
            f16x8 vf = *(const f16x8*)&Vts[wcol + c * 16 + l16][quad * 8];
#pragma unroll
            for (int r = 0; r < 2; ++r) {
                f32x4 o = oacc[r][c];
#pragma unroll
                for (int g = 0; g < 4; ++g) o[g] *= al[r][g];
                oacc[r][c] = __builtin_amdgcn_mfma_f32_16x16x32_f16(pf[r], vf, o, 0, 0, 0);
            }
        }
    }

    __syncthreads();
    const float norm = 0.04419417382415922f;   // 1/sqrt(512)
#pragma unroll
    for (int r = 0; r < 2; ++r)
#pragma unroll
        for (int g = 0; g < 4; ++g) {
            int row = r * 16 + quad * 4 + g;
            float scale = norm / row_l[row];
#pragma unroll
            for (int c = 0; c < 4; ++c)
                out[(size_t)(qbase + row) * DV + wcol + c * 16 + l16] = oacc[r][c][g] * scale;
        }
}

extern "C" void kernel_launch(void* const* d_in, const int* in_sizes, int n_in,
                              void* d_out, int out_size, void* d_ws, size_t ws_size,
                              hipStream_t stream) {
    const float* q  = (const float*)d_in[0];
    const float* k  = (const float*)d_in[1];
    const float* v  = (const float*)d_in[2];
    const float* Wq = (const float*)d_in[3];
    const float* bq = (const float*)d_in[4];
    const float* Wk = (const float*)d_in[5];
    const float* bk = (const float*)d_in[6];
    const float* Wv = (const float*)d_in[7];
    const float* bv = (const float*)d_in[8];

    _Float16* Qb = (_Float16*)d_ws;                    //  8 MB
    _Float16* Kb = Qb + (size_t)NQ * DK;               //  8 MB
    _Float16* Vt = Kb + (size_t)NKV * DK;              //  8 MB (transposed V)
    float* outp = (float*)d_out;

    proj_kernel<<<dim3(DK / 128, NQ / 128, 3), 256, 0, stream>>>(
        q, k, v, Wq, bq, Wk, bk, Wv, bv, Qb, Kb, Vt);
    flash_kernel<<<dim3(NQ / BQ), 512, 0, stream>>>(Qb, Kb, Vt, outp);
}

// Round 2
// 824.435 us; speedup vs baseline: 1.0401x; 1.0401x over previous
//
#include <hip/hip_runtime.h>
#include <hip/hip_bf16.h>

#define IN_DIM 1024
#define DK 512
#define DV 512
#define NQ 8192
#define NKV 8192
#define BQ 32
#define BK 128
#define NCH (NKV / BK)

typedef _Float16 f16x8 __attribute__((ext_vector_type(8)));
typedef _Float16 f16x4 __attribute__((ext_vector_type(4)));
typedef float f32x4 __attribute__((ext_vector_type(4)));

// ---------------- projection: out = A @ W^T + b, stored f16 ----------------
// z=0: Q[N][DK] row-major; z=1: K[M][DK] row-major; z=2: Vt[DV][M] (transposed)
__global__ __launch_bounds__(256) void proj_kernel(
    const float* __restrict__ qin, const float* __restrict__ kin, const float* __restrict__ vin,
    const float* __restrict__ Wq, const float* __restrict__ bq,
    const float* __restrict__ Wk, const float* __restrict__ bk,
    const float* __restrict__ Wv, const float* __restrict__ bv,
    _Float16* __restrict__ Qb, _Float16* __restrict__ Kb, _Float16* __restrict__ Vt)
{
    const int z = blockIdx.z;
    const float* A  = (z == 0) ? qin : (z == 1) ? kin : vin;
    const float* W  = (z == 0) ? Wq  : (z == 1) ? Wk  : Wv;
    const float* bi = (z == 0) ? bq  : (z == 1) ? bk  : bv;

    __shared__ _Float16 As[128][72];
    __shared__ _Float16 Bs[128][72];

    const int tid = threadIdx.x;
    const int rowbase = blockIdx.y * 128;
    const int colbase = blockIdx.x * 128;
    const int wave = tid >> 6;
    const int lane = tid & 63;
    const int quad = lane >> 4;
    const int l16  = lane & 15;
    const int wrow = (wave & 1) * 64;
    const int wcol = (wave >> 1) * 64;

    f32x4 acc[4][4];
#pragma unroll
    for (int r = 0; r < 4; ++r)
#pragma unroll
        for (int c = 0; c < 4; ++c) acc[r][c] = (f32x4)(0.0f);

    for (int kc = 0; kc < IN_DIM / 64; ++kc) {
        __syncthreads();
#pragma unroll
        for (int i = 0; i < 8; ++i) {
            int idx = tid + i * 256;
            int row = idx >> 4;
            int c4  = idx & 15;
            float4 ga = *(const float4*)&A[(size_t)(rowbase + row) * IN_DIM + kc * 64 + c4 * 4];
            f16x4 pa;
            pa[0] = (_Float16)ga.x; pa[1] = (_Float16)ga.y;
            pa[2] = (_Float16)ga.z; pa[3] = (_Float16)ga.w;
            *(f16x4*)&As[row][c4 * 4] = pa;
            float4 gb = *(const float4*)&W[(size_t)(colbase + row) * IN_DIM + kc * 64 + c4 * 4];
            f16x4 pb;
            pb[0] = (_Float16)gb.x; pb[1] = (_Float16)gb.y;
            pb[2] = (_Float16)gb.z; pb[3] = (_Float16)gb.w;
            *(f16x4*)&Bs[row][c4 * 4] = pb;
        }
        __syncthreads();
#pragma unroll
        for (int ks = 0; ks < 2; ++ks) {
            f16x8 af[4], bfr[4];
#pragma unroll
            for (int r = 0; r < 4; ++r)
                af[r] = *(const f16x8*)&As[wrow + r * 16 + l16][ks * 32 + quad * 8];
#pragma unroll
            for (int c = 0; c < 4; ++c)
                bfr[c] = *(const f16x8*)&Bs[wcol + c * 16 + l16][ks * 32 + quad * 8];
#pragma unroll
            for (int r = 0; r < 4; ++r)
#pragma unroll
                for (int c = 0; c < 4; ++c)
                    acc[r][c] = __builtin_amdgcn_mfma_f32_16x16x32_f16(af[r], bfr[c], acc[r][c], 0, 0, 0);
        }
    }

    if (z < 2) {
        _Float16* outp = (z == 0) ? Qb : Kb;
#pragma unroll
        for (int c = 0; c < 4; ++c) {
            int col = colbase + wcol + c * 16 + l16;
            float bval = bi[col];
#pragma unroll
            for (int r = 0; r < 4; ++r)
#pragma unroll
                for (int g = 0; g < 4; ++g) {
                    int row = rowbase + wrow + r * 16 + quad * 4 + g;
                    outp[(size_t)row * DK + col] = (_Float16)(acc[r][c][g] + bval);
                }
        }
    } else {
#pragma unroll
        for (int c = 0; c < 4; ++c) {
            int col = colbase + wcol + c * 16 + l16;
            float bval = bi[col];
#pragma unroll
            for (int r = 0; r < 4; ++r) {
                int row0 = rowbase + wrow + r * 16 + quad * 4;
                f16x4 pk;
#pragma unroll
                for (int g = 0; g < 4; ++g) pk[g] = (_Float16)(acc[r][c][g] + bval);
                *(f16x4*)&Vt[(size_t)col * NKV + row0] = pk;
            }
        }
    }
}

// ------- flash attention, zero-staging: K/V frags direct from global -------
// 512 threads = 8 waves. Wave w: S col-band = keys w*16..+15 of chunk;
// PV col-band = dv w*64..+63. Q held in registers (A-frag layout).
__global__ __launch_bounds__(512, 2) void flash_kernel(
    const _Float16* __restrict__ Qb, const _Float16* __restrict__ Kb,
    const _Float16* __restrict__ Vt, float* __restrict__ out)
{
    __shared__ _Float16 Ps[BQ][BK + 8];    // 8704 B, row stride 272 B (16B-aligned)
    __shared__ float Smax[BQ][12];         // partial row-max per col-band (pad->2-way)
    __shared__ float Ssum[BQ][12];
    __shared__ float row_m[2][BQ];
    __shared__ float row_l[2][BQ];

    const int tid  = threadIdx.x;
    const int w    = tid >> 6;
    const int lane = tid & 63;
    const int quad = lane >> 4;
    const int l16  = lane & 15;
    const int qbase = blockIdx.x * BQ;

    // ---- Q fragments in registers: qf[r][ks] covers rows r*16+l16, k=ks*32+quad*8
    f16x8 qf[2][16];
    {
        const _Float16* qp = Qb + (size_t)(qbase + l16) * DK + quad * 8;
#pragma unroll
        for (int ks = 0; ks < 16; ++ks) {
            qf[0][ks] = *(const f16x8*)(qp + ks * 32);
            qf[1][ks] = *(const f16x8*)(qp + 16 * DK + ks * 32);
        }
    }

    if (tid < BQ) { row_m[0][tid] = -1e30f; row_l[0][tid] = 0.0f; }

    f32x4 oacc[2][4];
#pragma unroll
    for (int r = 0; r < 2; ++r)
#pragma unroll
        for (int c = 0; c < 4; ++c) oacc[r][c] = (f32x4)(0.0f);

    const _Float16* kbasep = Kb + (size_t)(w * 16 + l16) * DK + quad * 8;
    const _Float16* vbasep = Vt + (size_t)(w * 64 + l16) * NKV + quad * 8;

    for (int kb = 0; kb < NCH; ++kb) {
        const int keybase = kb * BK;
        const int par = kb & 1;

        // ---- S = Q K^T for this wave's 16-key band (two 16-row tiles)
        f32x4 s0 = (f32x4)(0.0f), s1 = (f32x4)(0.0f);
        const _Float16* kp = kbasep + (size_t)keybase * DK;
#pragma unroll
        for (int ks = 0; ks < 16; ++ks) {
            f16x8 kf = *(const f16x8*)(kp + ks * 32);
            s0 = __builtin_amdgcn_mfma_f32_16x16x32_f16(qf[0][ks], kf, s0, 0, 0, 0);
            s1 = __builtin_amdgcn_mfma_f32_16x16x32_f16(qf[1][ks], kf, s1, 0, 0, 0);
        }

        // ---- per-row tile max (reduce over 16 cols = l16 lanes)
        float tmax[2][4];
#pragma unroll
        for (int g = 0; g < 4; ++g) {
            float m0 = s0[g], m1 = s1[g];
#pragma unroll
            for (int mask = 1; mask < 16; mask <<= 1) {
                m0 = fmaxf(m0, __shfl_xor(m0, mask));
                m1 = fmaxf(m1, __shfl_xor(m1, mask));
            }
            tmax[0][g] = m0; tmax[1][g] = m1;
        }
        if (l16 == 0) {
#pragma unroll
            for (int r = 0; r < 2; ++r)
#pragma unroll
                for (int g = 0; g < 4; ++g)
                    Smax[r * 16 + quad * 4 + g][w] = tmax[r][g];
        }
        __syncthreads();

        // ---- finalize max, exp, partial sums, write P (f16) for PV
        float alpha[2][4];
#pragma unroll
        for (int r = 0; r < 2; ++r)
#pragma unroll
            for (int g = 0; g < 4; ++g) {
                const int row = r * 16 + quad * 4 + g;
                f32x4 a0 = *(const f32x4*)&Smax[row][0];
                f32x4 a1 = *(const f32x4*)&Smax[row][4];
                float mt = fmaxf(fmaxf(fmaxf(a0[0], a0[1]), fmaxf(a0[2], a0[3])),
                                 fmaxf(fmaxf(a1[0], a1[1]), fmaxf(a1[2], a1[3])));
                float m_old = row_m[par][row];
                float m_new = fmaxf(mt, m_old);
                alpha[r][g] = __expf(m_old - m_new);
                float p = __expf(((r == 0) ? s0[g] : s1[g]) - m_new);
                float ts = p;
#pragma unroll
                for (int mask = 1; mask < 16; mask <<= 1)
                    ts += __shfl_xor(ts, mask);
                Ps[row][w * 16 + l16] = (_Float16)p;
                if (l16 == 0) {
                    Ssum[row][w] = ts;
                    if (w == 0) row_m[par ^ 1][row] = m_new;
                }
            }
        __syncthreads();

        // ---- running denominator (wave 0 only; consumed next chunk / at end)
        if (w == 0 && l16 == 0) {
#pragma unroll
            for (int r = 0; r < 2; ++r)
#pragma unroll
                for (int g = 0; g < 4; ++g) {
                    const int row = r * 16 + quad * 4 + g;
                    f32x4 u0 = *(const f32x4*)&Ssum[row][0];
                    f32x4 u1 = *(const f32x4*)&Ssum[row][4];
                    float s = (u0[0] + u0[1]) + (u0[2] + u0[3]) +
                              (u1[0] + u1[1]) + (u1[2] + u1[3]);
                    row_l[par ^ 1][row] = row_l[par][row] * alpha[r][g] + s;
                }
        }

        // ---- O rescale + PV (V frags direct from global, f16)
#pragma unroll
        for (int r = 0; r < 2; ++r)
#pragma unroll
            for (int c = 0; c < 4; ++c)
#pragma unroll
                for (int g = 0; g < 4; ++g) oacc[r][c][g] *= alpha[r][g];

        const _Float16* vp = vbasep + keybase;
#pragma unroll
        for (int ks = 0; ks < 4; ++ks) {
            f16x8 pf0 = *(const f16x8*)&Ps[l16][ks * 32 + quad * 8];
            f16x8 pf1 = *(const f16x8*)&Ps[16 + l16][ks * 32 + quad * 8];
#pragma unroll
            for (int c = 0; c < 4; ++c) {
                f16x8 vf = *(const f16x8*)(vp + (size_t)c * 16 * NKV + ks * 32);
                oacc[0][c] = __builtin_amdgcn_mfma_f32_16x16x32_f16(pf0, vf, oacc[0][c], 0, 0, 0);
                oacc[1][c] = __builtin_amdgcn_mfma_f32_16x16x32_f16(pf1, vf, oacc[1][c], 0, 0, 0);
            }
        }
    }

    __syncthreads();   // row_l[0] final (written by wave 0 last chunk)

    const float norm = 0.044194173824159216f;  // 1/sqrt(512), applied AFTER softmax
#pragma unroll
    for (int r = 0; r < 2; ++r)
#pragma unroll
        for (int g = 0; g < 4; ++g) {
            const int row = r * 16 + quad * 4 + g;
            const float sc = norm / row_l[0][row];
#pragma unroll
            for (int c = 0; c < 4; ++c)
                out[(size_t)(qbase + row) * DV + w * 64 + c * 16 + l16] = oacc[r][c][g] * sc;
        }
}

extern "C" void kernel_launch(void* const* d_in, const int* in_sizes, int n_in,
                              void* d_out, int out_size, void* d_ws, size_t ws_size,
                              hipStream_t stream) {
    const float* q  = (const float*)d_in[0];
    const float* k  = (const float*)d_in[1];
    const float* v  = (const float*)d_in[2];
    const float* Wq = (const float*)d_in[3];
    const float* bq = (const float*)d_in[4];
    const float* Wk = (const float*)d_in[5];
    const float* bk = (const float*)d_in[6];
    const float* Wv = (const float*)d_in[7];
    const float* bv = (const float*)d_in[8];

    _Float16* Qb = (_Float16*)d_ws;
    _Float16* Kb = Qb + (size_t)NQ * DK;
    _Float16* Vt = Kb + (size_t)NKV * DK;
    float* outp = (float*)d_out;

    proj_kernel<<<dim3(DK / 128, NQ / 128, 3), 256, 0, stream>>>(
        q, k, v, Wq, bq, Wk, bk, Wv, bv, Qb, Kb, Vt);
    flash_kernel<<<dim3(NQ / BQ), 512, 0, stream>>>(Qb, Kb, Vt, outp);
}